// Round 13
// baseline (149.647 us; speedup 1.0000x reference)
//
#include <hip/hip_runtime.h>

// LeNet forward, BATCH=4096. trunc = zero low 13 bits of fp32 mantissa.
// conv2 & fc1 via fp16 hi/lo-split MFMA. conv2 packs hi/lo INTO K
// (K = 25 pixels x 40 slots [20 a*w_hi | 20 a*w_lo], pad 1024 = 32 steps);
// B read straight from L2 with EXPLICIT 2-deep register double-buffer
// (compiler won't pipeline on its own -- R11 evidence: VGPR=104, util 25%).
// ws layout (bytes):
//   p1h  [4096][144][40] fp16 @ 0            (47,185,920)
//   p2h  [4096][800]     fp16 @ 47,185,920   ( 6,553,600)
//   h1h  [4096][512]     fp16 @ 53,739,520   ( 4,194,304)
//   wpc2 [32][64][32]    fp16 @ 57,933,824   (   131,072)
//   wpf1 [25][512][64]   fp16 @ 58,064,896   ( 1,638,400)

typedef _Float16 v8h __attribute__((ext_vector_type(8)));
typedef float v4f __attribute__((ext_vector_type(4)));

__device__ __forceinline__ float trunc13(float v) {
    return __int_as_float(__float_as_int(v) & (int)0xFFFFE000u);
}

// ---------------------------------------------------------------------------
// K0a: conv2 packed weights wp[t][oc][s]:  k=t*32+s, o=4t+(s>>3), pix=o/5,
// oi=o%5, r=oi*8+(s&7): r<20 -> hi(w[oc][r][pix]); else lo(w[oc][r-20][pix]).
// ---------------------------------------------------------------------------
__global__ void k_wprep(const float* __restrict__ w2, _Float16* __restrict__ wp) {
    int id = blockIdx.x * 256 + threadIdx.x;
    if (id >= 2048) return;
    int t = id >> 6, oc = id & 63;
    _Float16* dst = wp + (size_t)id * 32;
    for (int s = 0; s < 32; ++s) {
        int kg = s >> 3, j = s & 7;
        int o = 4 * t + kg;
        int pix = (o * 205) >> 10;          // /5, valid for o<128
        int oi = o - 5 * pix;
        int r = oi * 8 + j;
        _Float16 v = (_Float16)0.f;
        if (pix < 25 && oc < 50) {
            int ic = (r < 20) ? r : r - 20;
            float w = w2[oc * 500 + ic * 25 + pix];
            _Float16 hi = (_Float16)w;
            v = (r < 20) ? hi : (_Float16)(w - (float)hi);
        }
        dst[s] = v;
    }
}

// ---------------------------------------------------------------------------
// K0b: fc1 weight prep: wp1[t][oc][kk]=hi(W[oc][t*32+kk]), [32+kk]=lo
// ---------------------------------------------------------------------------
__global__ void k_w1prep(const float* __restrict__ W, _Float16* __restrict__ Bp) {
    int id = blockIdx.x * 256 + threadIdx.x;   // 25*512 = 12800
    if (id >= 12800) return;
    int t = id >> 9, oc = id & 511;
    _Float16* dst = Bp + (size_t)id * 64;
    for (int kk = 0; kk < 32; ++kk) {
        float w = (oc < 500) ? W[(size_t)oc * 800 + t * 32 + kk] : 0.f;
        _Float16 hi = (_Float16)w;
        _Float16 lo = (_Float16)(w - (float)hi);
        dst[kk] = hi;
        dst[32 + kk] = lo;
    }
}

// ---------------------------------------------------------------------------
// K1: conv1 + bias + trunc + relu + 2x2 maxpool -> fp16 [img][pos][40]
// (activations duplicated at +20 for conv2's fused hi/lo K packing)
// ---------------------------------------------------------------------------
__global__ __launch_bounds__(256) void k_conv1(const float* __restrict__ x,
                                               const float* __restrict__ w1,
                                               const float* __restrict__ b1,
                                               _Float16* __restrict__ p1h) {
    __shared__ float wsm[500];
    __shared__ float bsm[20];
    int tid = threadIdx.x;
    for (int t = tid; t < 500; t += 256) wsm[t] = w1[t];
    if (tid < 20) bsm[tid] = b1[tid];
    __syncthreads();

    int gid = blockIdx.x * 256 + tid;   // 4096*144 = 2304*256 exact
    int b   = gid / 144;
    int pos = gid % 144;
    int py = pos / 12, px = pos % 12;
    const float* img = x + (size_t)b * 784;

    float patch[36];
#pragma unroll
    for (int r = 0; r < 6; ++r)
#pragma unroll
        for (int c = 0; c < 6; ++c)
            patch[r * 6 + c] = img[(2 * py + r) * 28 + 2 * px + c];

    __align__(16) _Float16 hv[40];

    for (int oc = 0; oc < 20; ++oc) {
        float bias = bsm[oc];
        float s00 = bias, s01 = bias, s10 = bias, s11 = bias;
        const float* w = &wsm[oc * 25];
#pragma unroll
        for (int ky = 0; ky < 5; ++ky)
#pragma unroll
            for (int kx = 0; kx < 5; ++kx) {
                float wv = w[ky * 5 + kx];
                s00 += patch[ky * 6 + kx] * wv;
                s01 += patch[ky * 6 + kx + 1] * wv;
                s10 += patch[(ky + 1) * 6 + kx] * wv;
                s11 += patch[(ky + 1) * 6 + kx + 1] * wv;
            }
        float m = fmaxf(fmaxf(fmaxf(trunc13(s00), 0.f), fmaxf(trunc13(s01), 0.f)),
                        fmaxf(fmaxf(trunc13(s10), 0.f), fmaxf(trunc13(s11), 0.f)));
        _Float16 h = (_Float16)m;
        hv[oc] = h;
        hv[oc + 20] = h;
    }
    uint4* outp = (uint4*)(p1h + ((size_t)b * 144 + pos) * 40);
    const uint4* src = (const uint4*)hv;
#pragma unroll
    for (int i = 0; i < 5; ++i) outp[i] = src[i];
}

// ---------------------------------------------------------------------------
// K2: conv2 via MFMA 16x16x32_f16, fused hi/lo-in-K, fused pool epilogue.
// Block = 4 images, 4 waves (wave = image). A staged ONCE in LDS; B from
// L2. K-loop barrier-free with EXPLICIT P/Q register double-buffer, 2-deep:
// consume(P_t) trails load(P<-t) by 2 MFMA blocks (~154 cyc) -> L2 latency
// hidden without relying on compiler pipelining.
// ---------------------------------------------------------------------------
#define AIMG2 6240   // 156 pixel slots * 40 halfs
__global__ __launch_bounds__(256) void k_conv2(const _Float16* __restrict__ p1h,
                                               const _Float16* __restrict__ wp,
                                               const float* __restrict__ b2,
                                               _Float16* __restrict__ p2h) {
    __shared__ __align__(16) _Float16 Al[4 * AIMG2];   // 49920 B
    int tid = threadIdx.x;
    int b0 = blockIdx.x * 4;

    // A staging: 4 img x 720 uint4 copy + 60 uint4 zero pad each
    {
        const uint4* src = (const uint4*)(p1h + (size_t)b0 * 5760);
        uint4* dst = (uint4*)Al;
        uint4 z = make_uint4(0u, 0u, 0u, 0u);
        for (int i = tid; i < 3120; i += 256) {
            int img = i / 780, r = i - img * 780;
            dst[i] = (r < 720) ? src[img * 720 + r] : z;
        }
    }
    __syncthreads();

    int wid = tid >> 6, lane = tid & 63;
    int kg = lane >> 4, rr = lane & 15;
    int Y = rr >> 3, xx = rr & 7;
    const _Float16* Ab = Al + wid * AIMG2;
    const _Float16* abase[4];
#pragma unroll
    for (int my = 0; my < 4; ++my)
        abase[my] = Ab + ((2 * my + Y) * 12 + xx) * 40;
    const _Float16* wb = wp + rr * 32 + kg * 8;   // + t*2048 + nt*512

    v4f acc[4][4];
#pragma unroll
    for (int my = 0; my < 4; ++my)
#pragma unroll
        for (int nt = 0; nt < 4; ++nt) acc[my][nt] = (v4f){0.f, 0.f, 0.f, 0.f};

    v8h afP[4], bvP[4], afQ[4], bvQ[4];

#define LOADT(T, AF, BV)                                                     \
    {                                                                        \
        int o = 4 * (T) + kg;                                                \
        int pix = (o * 205) >> 10;                                           \
        int oi = o - 5 * pix;                                                \
        int ky = (pix * 205) >> 10;                                          \
        int kx = pix - 5 * ky;                                               \
        int aofs = (ky * 12 + kx) * 40 + oi * 8;                             \
        _Pragma("unroll")                                                    \
        for (int my = 0; my < 4; ++my)                                       \
            AF[my] = *(const v8h*)(abase[my] + aofs);                        \
        _Pragma("unroll")                                                    \
        for (int nt = 0; nt < 4; ++nt)                                       \
            BV[nt] = *(const v8h*)(wb + (T) * 2048 + nt * 512);              \
    }
#define MFMAS(AF, BV)                                                        \
    {                                                                        \
        _Pragma("unroll")                                                    \
        for (int my = 0; my < 4; ++my)                                       \
            _Pragma("unroll")                                                 \
            for (int nt = 0; nt < 4; ++nt)                                   \
                acc[my][nt] = __builtin_amdgcn_mfma_f32_16x16x32_f16(        \
                    AF[my], BV[nt], acc[my][nt], 0, 0, 0);                   \
    }

    LOADT(0, afP, bvP);
    LOADT(1, afQ, bvQ);
#pragma unroll
    for (int tt = 0; tt < 16; ++tt) {
        int t0 = 2 * tt;
        MFMAS(afP, bvP);
        if (t0 + 2 < 32) LOADT(t0 + 2, afP, bvP);
        MFMAS(afQ, bvQ);
        if (t0 + 3 < 32) LOADT(t0 + 3, afQ, bvQ);
    }
#undef LOADT
#undef MFMAS

    // epilogue: bias + trunc + relu, 2x2 pool (lane-local + xor32) -> fp16
    int imgg = b0 + wid;
#pragma unroll
    for (int nt = 0; nt < 4; ++nt) {
        int oc = nt * 16 + rr;
        float bias = (oc < 50) ? b2[oc] : 0.f;
#pragma unroll
        for (int my = 0; my < 4; ++my) {
            float z0 = fmaxf(trunc13(acc[my][nt][0] + bias), 0.f);
            float z1 = fmaxf(trunc13(acc[my][nt][1] + bias), 0.f);
            float z2 = fmaxf(trunc13(acc[my][nt][2] + bias), 0.f);
            float z3 = fmaxf(trunc13(acc[my][nt][3] + bias), 0.f);
            float s0 = fmaxf(z0, z1), s2 = fmaxf(z2, z3);
            float o0 = fmaxf(s0, __shfl_xor(s0, 32, 64));
            float o2 = fmaxf(s2, __shfl_xor(s2, 32, 64));
            if (kg < 2 && oc < 50) {
                p2h[(size_t)imgg * 800 + oc * 16 + my * 4 + 2 * kg]     = (_Float16)o0;
                p2h[(size_t)imgg * 800 + oc * 16 + my * 4 + 2 * kg + 1] = (_Float16)o2;
            }
        }
    }
}

// ---------------------------------------------------------------------------
// K3: fc1 via MFMA 16x16x32_f16, hi/lo split.  A:[4096,800]fp16 -> H fp16.
// BM=128 BN=64 BK=32, grid 32x8, 4 waves; XOR-swizzled LDS; T14 dbuf.
// ---------------------------------------------------------------------------
__global__ __launch_bounds__(256) void k_fc1(const _Float16* __restrict__ Ah,
                                             const _Float16* __restrict__ Bp,
                                             const float* __restrict__ bias,
                                             _Float16* __restrict__ Hh) {
    __shared__ _Float16 Al[2][4096];
    __shared__ _Float16 Bl[2][4096];
    int tid = threadIdx.x;
    int i0 = blockIdx.x * 128, n0 = blockIdx.y * 64;
    int wid = tid >> 6, lane = tid & 63;
    int rr = lane & 15, kg = lane >> 4;

    int ca0 = tid, ca1 = tid + 256;
    int ra0_ = ca0 >> 2, qa0 = ca0 & 3, ra1_ = ca1 >> 2, qa1 = ca1 & 3;
    int cb0 = tid, cb1 = tid + 256;
    int rb0_ = cb0 >> 3, qb0 = cb0 & 7, rb1_ = cb1 >> 3, qb1 = cb1 & 7;
    int aw0 = (ra0_ * 4 + (qa0 ^ ((ra0_ >> 1) & 3))) * 8;
    int aw1 = (ra1_ * 4 + (qa1 ^ ((ra1_ >> 1) & 3))) * 8;
    int bw0 = (rb0_ * 8 + (qb0 ^ (rb0_ & 7))) * 8;
    int bw1 = (rb1_ * 8 + (qb1 ^ (rb1_ & 7))) * 8;

    uint4 xa0, xa1, xb0, xb1;
    auto loadT = [&](int t) {
        xa0 = *(const uint4*)(Ah + (size_t)(i0 + ra0_) * 800 + t * 32 + qa0 * 8);
        xa1 = *(const uint4*)(Ah + (size_t)(i0 + ra1_) * 800 + t * 32 + qa1 * 8);
        const uint4* g = (const uint4*)(Bp + ((size_t)t * 512 + n0) * 64);
        xb0 = g[cb0]; xb1 = g[cb1];
    };
    auto writeT = [&](int buf) {
        *(uint4*)(&Al[buf][aw0]) = xa0;
        *(uint4*)(&Al[buf][aw1]) = xa1;
        *(uint4*)(&Bl[buf][bw0]) = xb0;
        *(uint4*)(&Bl[buf][bw1]) = xb1;
    };

    int aoff[2], bhoff[4], bloff[4];
#pragma unroll
    for (int mf = 0; mf < 2; ++mf) {
        int r = wid * 32 + mf * 16 + rr;
        aoff[mf] = (r * 4 + (kg ^ ((rr >> 1) & 3))) * 8;
    }
#pragma unroll
    for (int nf = 0; nf < 4; ++nf) {
        int r = nf * 16 + rr;
        bhoff[nf] = (r * 8 + (kg ^ (rr & 7))) * 8;
        bloff[nf] = (r * 8 + ((kg + 4) ^ (rr & 7))) * 8;
    }

    v4f zero = {0.f, 0.f, 0.f, 0.f};
    v4f acc[2][4];
#pragma unroll
    for (int mf = 0; mf < 2; ++mf)
#pragma unroll
        for (int nf = 0; nf < 4; ++nf) acc[mf][nf] = zero;

    loadT(0);
    writeT(0);
    __syncthreads();

    for (int t = 0; t < 25; ++t) {
        int cur = t & 1;
        if (t < 24) loadT(t + 1);
        v8h af[2], bh[4], bl[4];
#pragma unroll
        for (int mf = 0; mf < 2; ++mf) af[mf] = *(const v8h*)(&Al[cur][aoff[mf]]);
#pragma unroll
        for (int nf = 0; nf < 4; ++nf) {
            bh[nf] = *(const v8h*)(&Bl[cur][bhoff[nf]]);
            bl[nf] = *(const v8h*)(&Bl[cur][bloff[nf]]);
        }
#pragma unroll
        for (int mf = 0; mf < 2; ++mf)
#pragma unroll
            for (int nf = 0; nf < 4; ++nf) {
                acc[mf][nf] = __builtin_amdgcn_mfma_f32_16x16x32_f16(af[mf], bh[nf], acc[mf][nf], 0, 0, 0);
                acc[mf][nf] = __builtin_amdgcn_mfma_f32_16x16x32_f16(af[mf], bl[nf], acc[mf][nf], 0, 0, 0);
            }
        if (t < 24) writeT(cur ^ 1);
        __syncthreads();
    }

#pragma unroll
    for (int mf = 0; mf < 2; ++mf)
#pragma unroll
        for (int nf = 0; nf < 4; ++nf) {
            int col = n0 + nf * 16 + rr;
            float bs = bias[col < 500 ? col : 0];
#pragma unroll
            for (int j = 0; j < 4; ++j) {
                int row = i0 + wid * 32 + mf * 16 + kg * 4 + j;
                float v = fmaxf(trunc13(acc[mf][nf][j] + bs), 0.f);
                if (col < 500) Hh[(size_t)row * 512 + col] = (_Float16)v;
            }
        }
}

// ---------------------------------------------------------------------------
// K4: fc2 (500->10) + bias + trunc + log_softmax.  One wave per row, fp16 H.
// ---------------------------------------------------------------------------
__global__ __launch_bounds__(256) void k_fc2(const _Float16* __restrict__ Hh,
                                             const float* __restrict__ W,
                                             const float* __restrict__ bias,
                                             float* __restrict__ out) {
    int wave = threadIdx.x >> 6;
    int lane = threadIdx.x & 63;
    int i = blockIdx.x * 4 + wave;
    const _Float16* hrow = Hh + (size_t)i * 512;

    float p[10];
#pragma unroll
    for (int j = 0; j < 10; ++j) p[j] = 0.f;
    for (int k = lane; k < 500; k += 64) {
        float h = (float)hrow[k];
#pragma unroll
        for (int j = 0; j < 10; ++j) p[j] += h * W[j * 500 + k];
    }
#pragma unroll
    for (int j = 0; j < 10; ++j)
#pragma unroll
        for (int off = 32; off; off >>= 1) p[j] += __shfl_xor(p[j], off, 64);

    if (lane == 0) {
        float z[10], m = -1e30f;
#pragma unroll
        for (int j = 0; j < 10; ++j) {
            z[j] = trunc13(p[j] + bias[j]);
            m = fmaxf(m, z[j]);
        }
        float s = 0.f;
#pragma unroll
        for (int j = 0; j < 10; ++j) s += expf(z[j] - m);
        float lse = m + logf(s);
#pragma unroll
        for (int j = 0; j < 10; ++j) out[(size_t)i * 10 + j] = z[j] - lse;
    }
}

// ---------------------------------------------------------------------------
extern "C" void kernel_launch(void* const* d_in, const int* in_sizes, int n_in,
                              void* d_out, int out_size, void* d_ws, size_t ws_size,
                              hipStream_t stream) {
    const float* x   = (const float*)d_in[0];
    const float* w1  = (const float*)d_in[1];
    const float* b1  = (const float*)d_in[2];
    const float* w2  = (const float*)d_in[3];
    const float* b2  = (const float*)d_in[4];
    const float* wf1 = (const float*)d_in[5];
    const float* bf1 = (const float*)d_in[6];
    const float* wf2 = (const float*)d_in[7];
    const float* bf2 = (const float*)d_in[8];
    float* out = (float*)d_out;

    char* ws = (char*)d_ws;
    _Float16* p1h  = (_Float16*)(ws);                   // 47,185,920
    _Float16* p2h  = (_Float16*)(ws + 47185920);        //  6,553,600
    _Float16* h1h  = (_Float16*)(ws + 53739520);        //  4,194,304
    _Float16* wpc2 = (_Float16*)(ws + 57933824);        //    131,072
    _Float16* wpf1 = (_Float16*)(ws + 58064896);        //  1,638,400

    k_wprep<<<8, 256, 0, stream>>>(w2, wpc2);
    k_w1prep<<<50, 256, 0, stream>>>(wf1, wpf1);
    k_conv1<<<2304, 256, 0, stream>>>(x, w1, b1, p1h);
    k_conv2<<<1024, 256, 0, stream>>>(p1h, wpc2, b2, p2h);
    dim3 g3(32, 8);
    k_fc1<<<g3, 256, 0, stream>>>(p2h, wpf1, bf1, h1h);
    k_fc2<<<1024, 256, 0, stream>>>(h1h, wf2, bf2, out);
}

// Round 14
// 147.377 us; speedup vs baseline: 1.0154x; 1.0154x over previous
//
#include <hip/hip_runtime.h>

// LeNet forward, BATCH=4096. trunc = zero low 13 bits of fp32 mantissa.
// conv2 & fc1 via fp16 hi/lo-split MFMA. conv2 packs hi/lo INTO K
// (K = 25 pixels x 40 slots [20 a*w_hi | 20 a*w_lo], pad 1024 = 32 steps);
// B from L2; latency hidden by TLP (8 waves/block, wave = (img, N-half)),
// NOT by source-level pipelining (R12/R13: compiler re-sinks prefetches).
// ws layout (bytes):
//   p1h  [4096][144][40] fp16 @ 0            (47,185,920)
//   p2h  [4096][800]     fp16 @ 47,185,920   ( 6,553,600)
//   h1h  [4096][512]     fp16 @ 53,739,520   ( 4,194,304)
//   wpc2 [32][64][32]    fp16 @ 57,933,824   (   131,072)
//   wpf1 [25][512][64]   fp16 @ 58,064,896   ( 1,638,400)

typedef _Float16 v8h __attribute__((ext_vector_type(8)));
typedef float v4f __attribute__((ext_vector_type(4)));

__device__ __forceinline__ float trunc13(float v) {
    return __int_as_float(__float_as_int(v) & (int)0xFFFFE000u);
}

// ---------------------------------------------------------------------------
// K0a: conv2 packed weights wp[t][oc][s]:  k=t*32+s, o=4t+(s>>3), pix=o/5,
// oi=o%5, r=oi*8+(s&7): r<20 -> hi(w[oc][r][pix]); else lo(w[oc][r-20][pix]).
// ---------------------------------------------------------------------------
__global__ void k_wprep(const float* __restrict__ w2, _Float16* __restrict__ wp) {
    int id = blockIdx.x * 256 + threadIdx.x;
    if (id >= 2048) return;
    int t = id >> 6, oc = id & 63;
    _Float16* dst = wp + (size_t)id * 32;
    for (int s = 0; s < 32; ++s) {
        int kg = s >> 3, j = s & 7;
        int o = 4 * t + kg;
        int pix = (o * 205) >> 10;          // /5, valid for o<128
        int oi = o - 5 * pix;
        int r = oi * 8 + j;
        _Float16 v = (_Float16)0.f;
        if (pix < 25 && oc < 50) {
            int ic = (r < 20) ? r : r - 20;
            float w = w2[oc * 500 + ic * 25 + pix];
            _Float16 hi = (_Float16)w;
            v = (r < 20) ? hi : (_Float16)(w - (float)hi);
        }
        dst[s] = v;
    }
}

// ---------------------------------------------------------------------------
// K0b: fc1 weight prep: wp1[t][oc][kk]=hi(W[oc][t*32+kk]), [32+kk]=lo
// ---------------------------------------------------------------------------
__global__ void k_w1prep(const float* __restrict__ W, _Float16* __restrict__ Bp) {
    int id = blockIdx.x * 256 + threadIdx.x;   // 25*512 = 12800
    if (id >= 12800) return;
    int t = id >> 9, oc = id & 511;
    _Float16* dst = Bp + (size_t)id * 64;
    for (int kk = 0; kk < 32; ++kk) {
        float w = (oc < 500) ? W[(size_t)oc * 800 + t * 32 + kk] : 0.f;
        _Float16 hi = (_Float16)w;
        _Float16 lo = (_Float16)(w - (float)hi);
        dst[kk] = hi;
        dst[32 + kk] = lo;
    }
}

// ---------------------------------------------------------------------------
// K1: conv1 + bias + trunc + relu + 2x2 maxpool -> fp16 [img][pos][40]
// (activations duplicated at +20 for conv2's fused hi/lo K packing)
// ---------------------------------------------------------------------------
__global__ __launch_bounds__(256) void k_conv1(const float* __restrict__ x,
                                               const float* __restrict__ w1,
                                               const float* __restrict__ b1,
                                               _Float16* __restrict__ p1h) {
    __shared__ float wsm[500];
    __shared__ float bsm[20];
    int tid = threadIdx.x;
    for (int t = tid; t < 500; t += 256) wsm[t] = w1[t];
    if (tid < 20) bsm[tid] = b1[tid];
    __syncthreads();

    int gid = blockIdx.x * 256 + tid;   // 4096*144 = 2304*256 exact
    int b   = gid / 144;
    int pos = gid % 144;
    int py = pos / 12, px = pos % 12;
    const float* img = x + (size_t)b * 784;

    float patch[36];
#pragma unroll
    for (int r = 0; r < 6; ++r)
#pragma unroll
        for (int c = 0; c < 6; ++c)
            patch[r * 6 + c] = img[(2 * py + r) * 28 + 2 * px + c];

    __align__(16) _Float16 hv[40];

    for (int oc = 0; oc < 20; ++oc) {
        float bias = bsm[oc];
        float s00 = bias, s01 = bias, s10 = bias, s11 = bias;
        const float* w = &wsm[oc * 25];
#pragma unroll
        for (int ky = 0; ky < 5; ++ky)
#pragma unroll
            for (int kx = 0; kx < 5; ++kx) {
                float wv = w[ky * 5 + kx];
                s00 += patch[ky * 6 + kx] * wv;
                s01 += patch[ky * 6 + kx + 1] * wv;
                s10 += patch[(ky + 1) * 6 + kx] * wv;
                s11 += patch[(ky + 1) * 6 + kx + 1] * wv;
            }
        float m = fmaxf(fmaxf(fmaxf(trunc13(s00), 0.f), fmaxf(trunc13(s01), 0.f)),
                        fmaxf(fmaxf(trunc13(s10), 0.f), fmaxf(trunc13(s11), 0.f)));
        _Float16 h = (_Float16)m;
        hv[oc] = h;
        hv[oc + 20] = h;
    }
    uint4* outp = (uint4*)(p1h + ((size_t)b * 144 + pos) * 40);
    const uint4* src = (const uint4*)hv;
#pragma unroll
    for (int i = 0; i < 5; ++i) outp[i] = src[i];
}

// ---------------------------------------------------------------------------
// K2: conv2 via MFMA 16x16x32_f16, fused hi/lo-in-K, fused pool epilogue.
// 512 thr = 8 waves over 4 LDS-staged images: wave = (img = w>>1, nh = w&1);
// my=4 (full image M=64), nt=2 (oc half). Per-wave B traffic 64 KB from L2.
// 49.9 KB LDS -> 3 blocks/CU; ~4 waves/SIMD at ~100 VGPR -> TLP hides L2.
// ---------------------------------------------------------------------------
#define AIMG2 6240   // 156 pixel slots * 40 halfs
__global__ __launch_bounds__(512, 2) void k_conv2(const _Float16* __restrict__ p1h,
                                                  const _Float16* __restrict__ wp,
                                                  const float* __restrict__ b2,
                                                  _Float16* __restrict__ p2h) {
    __shared__ __align__(16) _Float16 Al[4 * AIMG2];   // 49920 B
    int tid = threadIdx.x;
    int b0 = blockIdx.x * 4;

    // A staging: 4 img x 720 uint4 copy + 60 uint4 zero pad each
    {
        const uint4* src = (const uint4*)(p1h + (size_t)b0 * 5760);
        uint4* dst = (uint4*)Al;
        uint4 z = make_uint4(0u, 0u, 0u, 0u);
        for (int i = tid; i < 3120; i += 512) {
            int img = i / 780, r = i - img * 780;
            dst[i] = (r < 720) ? src[img * 720 + r] : z;
        }
    }
    __syncthreads();

    int wid = tid >> 6, lane = tid & 63;
    int img = wid >> 1, nh = wid & 1;
    int kg = lane >> 4, rr = lane & 15;
    int Y = rr >> 3, xx = rr & 7;
    const _Float16* Ab = Al + img * AIMG2;
    const _Float16* abase[4];
#pragma unroll
    for (int my = 0; my < 4; ++my)
        abase[my] = Ab + ((2 * my + Y) * 12 + xx) * 40;
    // B base for this wave's two oc-tiles: ntg = nh*2 + {0,1}
    const _Float16* wb = wp + (size_t)(nh * 2) * 512 + rr * 32 + kg * 8;

    v4f acc[4][2];
#pragma unroll
    for (int my = 0; my < 4; ++my)
#pragma unroll
        for (int nt = 0; nt < 2; ++nt) acc[my][nt] = (v4f){0.f, 0.f, 0.f, 0.f};

#pragma unroll 2
    for (int t = 0; t < 32; ++t) {
        int o = 4 * t + kg;
        int pix = (o * 205) >> 10;       // /5
        int oi = o - 5 * pix;
        int ky = (pix * 205) >> 10;      // /5
        int kx = pix - 5 * ky;
        int aofs = (ky * 12 + kx) * 40 + oi * 8;
        v8h af[4];
#pragma unroll
        for (int my = 0; my < 4; ++my)
            af[my] = *(const v8h*)(abase[my] + aofs);
        v8h bv[2];
#pragma unroll
        for (int nt = 0; nt < 2; ++nt)
            bv[nt] = *(const v8h*)(wb + t * 2048 + nt * 512);
#pragma unroll
        for (int my = 0; my < 4; ++my)
#pragma unroll
            for (int nt = 0; nt < 2; ++nt)
                acc[my][nt] = __builtin_amdgcn_mfma_f32_16x16x32_f16(af[my], bv[nt], acc[my][nt], 0, 0, 0);
    }

    // epilogue: bias + trunc + relu, 2x2 pool (lane-local + xor32) -> fp16
    int imgg = b0 + img;
#pragma unroll
    for (int nt = 0; nt < 2; ++nt) {
        int oc = (nh * 2 + nt) * 16 + rr;
        float bias = (oc < 50) ? b2[oc] : 0.f;
#pragma unroll
        for (int my = 0; my < 4; ++my) {
            float z0 = fmaxf(trunc13(acc[my][nt][0] + bias), 0.f);
            float z1 = fmaxf(trunc13(acc[my][nt][1] + bias), 0.f);
            float z2 = fmaxf(trunc13(acc[my][nt][2] + bias), 0.f);
            float z3 = fmaxf(trunc13(acc[my][nt][3] + bias), 0.f);
            float s0 = fmaxf(z0, z1), s2 = fmaxf(z2, z3);
            float o0 = fmaxf(s0, __shfl_xor(s0, 32, 64));
            float o2 = fmaxf(s2, __shfl_xor(s2, 32, 64));
            if (kg < 2 && oc < 50) {
                p2h[(size_t)imgg * 800 + oc * 16 + my * 4 + 2 * kg]     = (_Float16)o0;
                p2h[(size_t)imgg * 800 + oc * 16 + my * 4 + 2 * kg + 1] = (_Float16)o2;
            }
        }
    }
}

// ---------------------------------------------------------------------------
// K3: fc1 via MFMA 16x16x32_f16, hi/lo split.  A:[4096,800]fp16 -> H fp16.
// BM=128 BN=64 BK=32, grid 32x8, 4 waves; XOR-swizzled LDS; T14 dbuf.
// ---------------------------------------------------------------------------
__global__ __launch_bounds__(256) void k_fc1(const _Float16* __restrict__ Ah,
                                             const _Float16* __restrict__ Bp,
                                             const float* __restrict__ bias,
                                             _Float16* __restrict__ Hh) {
    __shared__ _Float16 Al[2][4096];
    __shared__ _Float16 Bl[2][4096];
    int tid = threadIdx.x;
    int i0 = blockIdx.x * 128, n0 = blockIdx.y * 64;
    int wid = tid >> 6, lane = tid & 63;
    int rr = lane & 15, kg = lane >> 4;

    int ca0 = tid, ca1 = tid + 256;
    int ra0_ = ca0 >> 2, qa0 = ca0 & 3, ra1_ = ca1 >> 2, qa1 = ca1 & 3;
    int cb0 = tid, cb1 = tid + 256;
    int rb0_ = cb0 >> 3, qb0 = cb0 & 7, rb1_ = cb1 >> 3, qb1 = cb1 & 7;
    int aw0 = (ra0_ * 4 + (qa0 ^ ((ra0_ >> 1) & 3))) * 8;
    int aw1 = (ra1_ * 4 + (qa1 ^ ((ra1_ >> 1) & 3))) * 8;
    int bw0 = (rb0_ * 8 + (qb0 ^ (rb0_ & 7))) * 8;
    int bw1 = (rb1_ * 8 + (qb1 ^ (rb1_ & 7))) * 8;

    uint4 xa0, xa1, xb0, xb1;
    auto loadT = [&](int t) {
        xa0 = *(const uint4*)(Ah + (size_t)(i0 + ra0_) * 800 + t * 32 + qa0 * 8);
        xa1 = *(const uint4*)(Ah + (size_t)(i0 + ra1_) * 800 + t * 32 + qa1 * 8);
        const uint4* g = (const uint4*)(Bp + ((size_t)t * 512 + n0) * 64);
        xb0 = g[cb0]; xb1 = g[cb1];
    };
    auto writeT = [&](int buf) {
        *(uint4*)(&Al[buf][aw0]) = xa0;
        *(uint4*)(&Al[buf][aw1]) = xa1;
        *(uint4*)(&Bl[buf][bw0]) = xb0;
        *(uint4*)(&Bl[buf][bw1]) = xb1;
    };

    int aoff[2], bhoff[4], bloff[4];
#pragma unroll
    for (int mf = 0; mf < 2; ++mf) {
        int r = wid * 32 + mf * 16 + rr;
        aoff[mf] = (r * 4 + (kg ^ ((rr >> 1) & 3))) * 8;
    }
#pragma unroll
    for (int nf = 0; nf < 4; ++nf) {
        int r = nf * 16 + rr;
        bhoff[nf] = (r * 8 + (kg ^ (rr & 7))) * 8;
        bloff[nf] = (r * 8 + ((kg + 4) ^ (rr & 7))) * 8;
    }

    v4f zero = {0.f, 0.f, 0.f, 0.f};
    v4f acc[2][4];
#pragma unroll
    for (int mf = 0; mf < 2; ++mf)
#pragma unroll
        for (int nf = 0; nf < 4; ++nf) acc[mf][nf] = zero;

    loadT(0);
    writeT(0);
    __syncthreads();

    for (int t = 0; t < 25; ++t) {
        int cur = t & 1;
        if (t < 24) loadT(t + 1);
        v8h af[2], bh[4], bl[4];
#pragma unroll
        for (int mf = 0; mf < 2; ++mf) af[mf] = *(const v8h*)(&Al[cur][aoff[mf]]);
#pragma unroll
        for (int nf = 0; nf < 4; ++nf) {
            bh[nf] = *(const v8h*)(&Bl[cur][bhoff[nf]]);
            bl[nf] = *(const v8h*)(&Bl[cur][bloff[nf]]);
        }
#pragma unroll
        for (int mf = 0; mf < 2; ++mf)
#pragma unroll
            for (int nf = 0; nf < 4; ++nf) {
                acc[mf][nf] = __builtin_amdgcn_mfma_f32_16x16x32_f16(af[mf], bh[nf], acc[mf][nf], 0, 0, 0);
                acc[mf][nf] = __builtin_amdgcn_mfma_f32_16x16x32_f16(af[mf], bl[nf], acc[mf][nf], 0, 0, 0);
            }
        if (t < 24) writeT(cur ^ 1);
        __syncthreads();
    }

#pragma unroll
    for (int mf = 0; mf < 2; ++mf)
#pragma unroll
        for (int nf = 0; nf < 4; ++nf) {
            int col = n0 + nf * 16 + rr;
            float bs = bias[col < 500 ? col : 0];
#pragma unroll
            for (int j = 0; j < 4; ++j) {
                int row = i0 + wid * 32 + mf * 16 + kg * 4 + j;
                float v = fmaxf(trunc13(acc[mf][nf][j] + bs), 0.f);
                if (col < 500) Hh[(size_t)row * 512 + col] = (_Float16)v;
            }
        }
}

// ---------------------------------------------------------------------------
// K4: fc2 (500->10) + bias + trunc + log_softmax.  One wave per row, fp16 H.
// ---------------------------------------------------------------------------
__global__ __launch_bounds__(256) void k_fc2(const _Float16* __restrict__ Hh,
                                             const float* __restrict__ W,
                                             const float* __restrict__ bias,
                                             float* __restrict__ out) {
    int wave = threadIdx.x >> 6;
    int lane = threadIdx.x & 63;
    int i = blockIdx.x * 4 + wave;
    const _Float16* hrow = Hh + (size_t)i * 512;

    float p[10];
#pragma unroll
    for (int j = 0; j < 10; ++j) p[j] = 0.f;
    for (int k = lane; k < 500; k += 64) {
        float h = (float)hrow[k];
#pragma unroll
        for (int j = 0; j < 10; ++j) p[j] += h * W[j * 500 + k];
    }
#pragma unroll
    for (int j = 0; j < 10; ++j)
#pragma unroll
        for (int off = 32; off; off >>= 1) p[j] += __shfl_xor(p[j], off, 64);

    if (lane == 0) {
        float z[10], m = -1e30f;
#pragma unroll
        for (int j = 0; j < 10; ++j) {
            z[j] = trunc13(p[j] + bias[j]);
            m = fmaxf(m, z[j]);
        }
        float s = 0.f;
#pragma unroll
        for (int j = 0; j < 10; ++j) s += expf(z[j] - m);
        float lse = m + logf(s);
#pragma unroll
        for (int j = 0; j < 10; ++j) out[(size_t)i * 10 + j] = z[j] - lse;
    }
}

// ---------------------------------------------------------------------------
extern "C" void kernel_launch(void* const* d_in, const int* in_sizes, int n_in,
                              void* d_out, int out_size, void* d_ws, size_t ws_size,
                              hipStream_t stream) {
    const float* x   = (const float*)d_in[0];
    const float* w1  = (const float*)d_in[1];
    const float* b1  = (const float*)d_in[2];
    const float* w2  = (const float*)d_in[3];
    const float* b2  = (const float*)d_in[4];
    const float* wf1 = (const float*)d_in[5];
    const float* bf1 = (const float*)d_in[6];
    const float* wf2 = (const float*)d_in[7];
    const float* bf2 = (const float*)d_in[8];
    float* out = (float*)d_out;

    char* ws = (char*)d_ws;
    _Float16* p1h  = (_Float16*)(ws);                   // 47,185,920
    _Float16* p2h  = (_Float16*)(ws + 47185920);        //  6,553,600
    _Float16* h1h  = (_Float16*)(ws + 53739520);        //  4,194,304
    _Float16* wpc2 = (_Float16*)(ws + 57933824);        //    131,072
    _Float16* wpf1 = (_Float16*)(ws + 58064896);        //  1,638,400

    k_wprep<<<8, 256, 0, stream>>>(w2, wpc2);
    k_w1prep<<<50, 256, 0, stream>>>(wf1, wpf1);
    k_conv1<<<2304, 256, 0, stream>>>(x, w1, b1, p1h);
    k_conv2<<<1024, 512, 0, stream>>>(p1h, wpc2, b2, p2h);
    dim3 g3(32, 8);
    k_fc1<<<g3, 256, 0, stream>>>(p2h, wpf1, bf1, h1h);
    k_fc2<<<1024, 256, 0, stream>>>(h1h, wf2, bf2, out);
}